// Round 2
// baseline (956.705 us; speedup 1.0000x reference)
//
#include <hip/hip_runtime.h>
#include <cstdint>

#define C_LEN 4096
#define E_DIM 1024
#define NBATCH 4

typedef __attribute__((ext_vector_type(4))) float f32x4;
typedef __attribute__((ext_vector_type(8))) short bf16x8;
typedef __attribute__((ext_vector_type(4))) unsigned short u16x4;

__device__ __forceinline__ unsigned short f2bf(float f) {
  uint32_t u = __builtin_bit_cast(uint32_t, f);
  return (unsigned short)((u + 0x7fffu + ((u >> 16) & 1u)) >> 16);
}

__device__ __forceinline__ void gl_lds16(const void* g, void* l) {
  __builtin_amdgcn_global_load_lds(
      (const __attribute__((address_space(1))) void*)g,
      (__attribute__((address_space(3))) void*)l, 16, 0, 0);
}

// -------- RoPE cos/sin table: [C][E/2] f32 each, computed in double --------
__global__ __launch_bounds__(256) void rope_table(float* __restrict__ cosT,
                                                  float* __restrict__ sinT) {
  int idx = blockIdx.x * 256 + threadIdx.x;  // over C*E/2 = 2,097,152
  int pos = idx >> 9;
  int i = idx & 511;
  double inv = exp(((double)(-2 * i) / 1024.0) * 9.210340371976184);
  double a = (double)pos * inv;
  cosT[idx] = (float)cos(a);
  sinT[idx] = (float)sin(a);
}

// -------- f32 -> bf16 convert (4 elems/thread) --------
__global__ __launch_bounds__(256) void cvt_bf16_k(const float* __restrict__ in,
                                                  unsigned short* __restrict__ out,
                                                  int n4) {
  int i = blockIdx.x * 256 + threadIdx.x;
  if (i < n4) {
    f32x4 v = *(const f32x4*)(in + (long)i * 4);
    u16x4 o = {f2bf(v.x), f2bf(v.y), f2bf(v.z), f2bf(v.w)};
    *(u16x4*)(out + (long)i * 4) = o;
  }
}

// -------- BT GEMM: A[M][K] bf16 row-major, B[N][K] bf16 row-major (B^T form) --------
// 128x128 tile, BK=32, 256 threads = 4 waves (2x2), each wave 64x64 (4x4 frags).
// MODE 0: fused QKV projection. N=3072 = [Q|K|V] sections; RoPE on Q/K, transpose-store V.
// MODE 2: epilogue *1/32 + mask, write f32 scores (QK^T)
// MODE 3: plain f32 out (PV: A = P_bf, B = V_t)
template <int MODE>
__global__ __launch_bounds__(256) void gemm_bt(
    const unsigned short* __restrict__ A, const unsigned short* __restrict__ Bm,
    long batchA, long batchB, long batchOut, int M, int N, int K,
    unsigned short* __restrict__ outQ, unsigned short* __restrict__ outK,
    unsigned short* __restrict__ outVt, float* __restrict__ outF,
    const float* __restrict__ cosT, const float* __restrict__ sinT,
    const float* __restrict__ mask) {
  __shared__ unsigned short sA[128 * 32];
  __shared__ unsigned short sB[128 * 32];
  const int tid = threadIdx.x;
  const int lane = tid & 63;
  const int wid = tid >> 6;
  const int wm = wid >> 1, wn = wid & 1;
  const int bz = blockIdx.z;
  const unsigned short* Ag = A + batchA * bz + (long)(blockIdx.x * 128) * K;
  const unsigned short* Bg = Bm + batchB * bz + (long)(blockIdx.y * 128) * K;
  const int srow = tid >> 2;       // staging row within 64-row half
  const int scol = (tid & 3) * 8;  // staging col (elements)

  f32x4 acc[4][4];
#pragma unroll
  for (int m = 0; m < 4; ++m)
#pragma unroll
    for (int n = 0; n < 4; ++n) acc[m][n] = {0.f, 0.f, 0.f, 0.f};

  const int kgrp = lane >> 4;
  const int r16 = lane & 15;

  for (int k0 = 0; k0 < K; k0 += 32) {
#pragma unroll
    for (int i = 0; i < 2; ++i) {
      gl_lds16(Ag + (long)(i * 64 + srow) * K + k0 + scol, sA + i * 2048 + wid * 512);
      gl_lds16(Bg + (long)(i * 64 + srow) * K + k0 + scol, sB + i * 2048 + wid * 512);
    }
    __syncthreads();  // compiler drains vmcnt before barrier -> staged data visible
    bf16x8 af[4], bfr[4];
#pragma unroll
    for (int m = 0; m < 4; ++m)
      af[m] = *(const bf16x8*)&sA[(wm * 64 + m * 16 + r16) * 32 + kgrp * 8];
#pragma unroll
    for (int n = 0; n < 4; ++n)
      bfr[n] = *(const bf16x8*)&sB[(wn * 64 + n * 16 + r16) * 32 + kgrp * 8];
#pragma unroll
    for (int m = 0; m < 4; ++m)
#pragma unroll
      for (int n = 0; n < 4; ++n)
        acc[m][n] = __builtin_amdgcn_mfma_f32_16x16x32_bf16(af[m], bfr[n], acc[m][n], 0, 0, 0);
    __syncthreads();  // all waves done reading before next stage overwrites
  }

  const int row0 = blockIdx.x * 128 + wm * 64;
  const int col0 = blockIdx.y * 128 + wn * 64;
#pragma unroll
  for (int m = 0; m < 4; ++m) {
#pragma unroll
    for (int n = 0; n < 4; ++n) {
#pragma unroll
      for (int r = 0; r < 4; ++r) {
        float v = acc[m][n][r];
        int row = row0 + m * 16 + kgrp * 4 + r;  // C/D: col=lane&15, row=(lane>>4)*4+r
        int col = col0 + n * 16 + r16;
        if (MODE == 0) {
          int sel = col >> 10;  // 0=Q 1=K 2=V (uniform per block: 128-tile never straddles)
          int lcol = col & 1023;
          if (sel < 2) {
            // RoPE: pair partner lives in lane^1 (col^1), same row/reg.
            float p = __shfl_xor(v, 1);
            int pos = row & (C_LEN - 1);
            int i2 = lcol >> 1;
            float c = cosT[pos * (E_DIM / 2) + i2];
            float s = sinT[pos * (E_DIM / 2) + i2];
            float rv = v * c + ((lcol & 1) ? p * s : -p * s);
            unsigned short* o = sel ? outK : outQ;
            o[(long)row * E_DIM + lcol] = f2bf(rv);
          } else {
            int b = row >> 12;  // C_LEN = 4096
            int cc = row & (C_LEN - 1);
            outVt[(long)b * E_DIM * C_LEN + (long)lcol * C_LEN + cc] = f2bf(v);
          }
        } else if (MODE == 2) {
          float sc = v * 0.03125f + mask[(long)row * C_LEN + col];
          outF[batchOut * bz + (long)row * C_LEN + col] = sc;
        } else {
          outF[batchOut * bz + (long)row * N + col] = v;
        }
      }
    }
  }
}

// -------- row softmax: normalize f32 weights in place + emit bf16 copy --------
__global__ __launch_bounds__(256) void softmax_rows(float* __restrict__ w,
                                                    unsigned short* __restrict__ pb) {
  long row = blockIdx.x;
  float* p = w + row * C_LEN;
  unsigned short* pbp = pb + row * C_LEN;
  int t = threadIdx.x;
  int wid = t >> 6;
  f32x4 v[4];
  float mx = -3.4e38f;
#pragma unroll
  for (int j = 0; j < 4; ++j) {
    v[j] = *(const f32x4*)(p + j * 1024 + t * 4);
    mx = fmaxf(mx, fmaxf(fmaxf(v[j].x, v[j].y), fmaxf(v[j].z, v[j].w)));
  }
#pragma unroll
  for (int o = 1; o < 64; o <<= 1) mx = fmaxf(mx, __shfl_xor(mx, o));
  __shared__ float redm[4];
  if ((t & 63) == 0) redm[wid] = mx;
  __syncthreads();
  mx = fmaxf(fmaxf(redm[0], redm[1]), fmaxf(redm[2], redm[3]));
  float sum = 0.f;
#pragma unroll
  for (int j = 0; j < 4; ++j) {
    v[j].x = __expf(v[j].x - mx);
    v[j].y = __expf(v[j].y - mx);
    v[j].z = __expf(v[j].z - mx);
    v[j].w = __expf(v[j].w - mx);
    sum += v[j].x + v[j].y + v[j].z + v[j].w;
  }
#pragma unroll
  for (int o = 1; o < 64; o <<= 1) sum += __shfl_xor(sum, o);
  __shared__ float reds[4];
  if ((t & 63) == 0) reds[wid] = sum;
  __syncthreads();
  sum = reds[0] + reds[1] + reds[2] + reds[3];
  float inv = 1.0f / sum;
#pragma unroll
  for (int j = 0; j < 4; ++j) {
    v[j].x *= inv;
    v[j].y *= inv;
    v[j].z *= inv;
    v[j].w *= inv;
    *(f32x4*)(p + j * 1024 + t * 4) = v[j];
    u16x4 o16 = {f2bf(v[j].x), f2bf(v[j].y), f2bf(v[j].z), f2bf(v[j].w)};
    *(u16x4*)(pbp + j * 1024 + t * 4) = o16;
  }
}

extern "C" void kernel_launch(void* const* d_in, const int* in_sizes, int n_in,
                              void* d_out, int out_size, void* d_ws, size_t ws_size,
                              hipStream_t stream) {
  const float* x = (const float*)d_in[0];
  const float* mask = (const float*)d_in[1];
  const float* Wq = (const float*)d_in[2];
  const float* Wk = (const float*)d_in[3];
  const float* Wv = (const float*)d_in[4];
  float* out = (float*)d_out;                           // [B][C][E]
  float* weights = out + (long)NBATCH * C_LEN * E_DIM;  // [B][C][C]

  // ws layout (150 MB total, same footprint as round 1):
  //   early region (dead after scores GEMM):
  //     cosT 0..8M, sinT 8..16M, x_bf 16..48M, W_bf 48..54M, Q_bf 54..86M, K_bf 86..118M
  //   persistent: Vt 118..150M
  //   P_bf (2 batches, 64 MB) reuses 0..64M after scores GEMM is done.
  char* ws = (char*)d_ws;
  float* cosT = (float*)(ws);
  float* sinT = (float*)(ws + (8l << 20));
  unsigned short* x_bf = (unsigned short*)(ws + (16l << 20));
  unsigned short* W_bf = (unsigned short*)(ws + (48l << 20));  // [3072][1024] = Q|K|V
  unsigned short* Q_bf = (unsigned short*)(ws + (54l << 20));
  unsigned short* K_bf = (unsigned short*)(ws + (86l << 20));
  unsigned short* Vt = (unsigned short*)(ws + (118l << 20));
  unsigned short* P_bf = (unsigned short*)(ws);  // 2-batch bf16 weights, reused region

  dim3 blk(256);

  rope_table<<<dim3((C_LEN * (E_DIM / 2)) / 256), blk, 0, stream>>>(cosT, sinT);
  cvt_bf16_k<<<dim3(16384), blk, 0, stream>>>(x, x_bf, 4194304);
  cvt_bf16_k<<<dim3(1024), blk, 0, stream>>>(Wq, W_bf, 262144);
  cvt_bf16_k<<<dim3(1024), blk, 0, stream>>>(Wk, W_bf + (1l << 20), 262144);
  cvt_bf16_k<<<dim3(1024), blk, 0, stream>>>(Wv, W_bf + (2l << 20), 262144);

  // fused QKV projection: x[16384][1024] @ W_bf^T[1024][3072]; RoPE on Q/K, V transposed
  gemm_bt<0><<<dim3(128, 24, 1), blk, 0, stream>>>(
      x_bf, W_bf, 0, 0, 0, NBATCH * C_LEN, 3 * E_DIM, E_DIM,
      Q_bf, K_bf, Vt, nullptr, cosT, sinT, nullptr);

  // scores = QK^T/32 + mask  -> weights region (f32)
  gemm_bt<2><<<dim3(32, 32, 4), blk, 0, stream>>>(
      Q_bf, K_bf, (long)C_LEN * E_DIM, (long)C_LEN * E_DIM, (long)C_LEN * C_LEN,
      C_LEN, C_LEN, E_DIM, nullptr, nullptr, nullptr, weights, nullptr, nullptr, mask);

  // softmax + PV in two 2-batch halves (P_bf region holds 2 batches)
  for (int h = 0; h < 2; ++h) {
    float* wgt = weights + (long)h * 2 * C_LEN * C_LEN;
    softmax_rows<<<dim3(2 * C_LEN), blk, 0, stream>>>(wgt, P_bf);
    gemm_bt<3><<<dim3(32, 8, 2), blk, 0, stream>>>(
        P_bf, Vt + (long)h * 2 * E_DIM * C_LEN, (long)C_LEN * C_LEN, (long)E_DIM * C_LEN,
        (long)C_LEN * E_DIM, C_LEN, E_DIM, C_LEN,
        nullptr, nullptr, nullptr, out + (long)h * 2 * C_LEN * E_DIM, nullptr, nullptr, nullptr);
  }
}

// Round 3
// 789.799 us; speedup vs baseline: 1.2113x; 1.2113x over previous
//
#include <hip/hip_runtime.h>
#include <cstdint>

#define C_LEN 4096
#define E_DIM 1024
#define NBATCH 4

typedef __attribute__((ext_vector_type(4))) float f32x4;
typedef __attribute__((ext_vector_type(8))) short bf16x8;
typedef __attribute__((ext_vector_type(4))) unsigned short u16x4;

__device__ __forceinline__ unsigned short f2bf(float f) {
  uint32_t u = __builtin_bit_cast(uint32_t, f);
  return (unsigned short)((u + 0x7fffu + ((u >> 16) & 1u)) >> 16);
}

__device__ __forceinline__ void gl_lds16(const void* g, void* l) {
  __builtin_amdgcn_global_load_lds(
      (const __attribute__((address_space(1))) void*)g,
      (__attribute__((address_space(3))) void*)l, 16, 0, 0);
}

// -------- RoPE cos/sin table: [C][E/2] f32 each, computed in double --------
__global__ __launch_bounds__(256) void rope_table(float* __restrict__ cosT,
                                                  float* __restrict__ sinT) {
  int idx = blockIdx.x * 256 + threadIdx.x;  // over C*E/2 = 2,097,152
  int pos = idx >> 9;
  int i = idx & 511;
  double inv = exp(((double)(-2 * i) / 1024.0) * 9.210340371976184);
  double a = (double)pos * inv;
  cosT[idx] = (float)cos(a);
  sinT[idx] = (float)sin(a);
}

// -------- f32 -> bf16 convert (4 elems/thread) --------
__global__ __launch_bounds__(256) void cvt_bf16_k(const float* __restrict__ in,
                                                  unsigned short* __restrict__ out,
                                                  int n4) {
  int i = blockIdx.x * 256 + threadIdx.x;
  if (i < n4) {
    f32x4 v = *(const f32x4*)(in + (long)i * 4);
    u16x4 o = {f2bf(v.x), f2bf(v.y), f2bf(v.z), f2bf(v.w)};
    *(u16x4*)(out + (long)i * 4) = o;
  }
}

// ======== 256x256 BT GEMM, BK=64, 512 threads = 8 waves (2M x 4N) ========
// Double-buffered LDS (128 KiB), prefetch-issue-before-compute, 1 barrier/K-tile.
// A[M][K] bf16 row-major, B[N][K] bf16 row-major (B^T form).
// MODE 0: fused QKV projection (N=3072 = [Q|K|V]); RoPE on Q/K, transpose-store V.
// MODE 2: epilogue *1/32 + mask, write f32 scores (QK^T)
// MODE 3: plain f32 out (PV)
template <int MODE>
__global__ __launch_bounds__(512, 2) void gemm256(
    const unsigned short* __restrict__ A, const unsigned short* __restrict__ Bm,
    long sAb, long sBb, long sOb, int nr, int nc, int K, int N,
    unsigned short* __restrict__ oQ, unsigned short* __restrict__ oK,
    unsigned short* __restrict__ oVt, float* __restrict__ oF,
    const float* __restrict__ cosT, const float* __restrict__ sinT,
    const float* __restrict__ mask) {
  __shared__ unsigned short sA[2][256 * 64];  // 2 x 32 KiB
  __shared__ unsigned short sB[2][256 * 64];  // 2 x 32 KiB  (128 KiB total)
  const int tid = threadIdx.x;
  const int lane = tid & 63;
  const int wid = tid >> 6;
  const int wm = wid >> 2, wn = wid & 3;
  const int kgrp = lane >> 4, r16 = lane & 15;

  // bijective XCD swizzle over linear grid (gridDim.x % 8 == 0 for all launches)
  const int nwg = gridDim.x;
  const int lid = blockIdx.x;
  const int s = (lid & 7) * (nwg >> 3) + (lid >> 3);
  const int per_b = nr * nc;
  const int bz = s / per_b;
  const int t2 = s - bz * per_b;
  const int rt = t2 / nc, ct = t2 - rt * nc;

  const unsigned short* Ag = A + sAb * bz + (long)rt * 256 * K;
  const unsigned short* Bg = Bm + sBb * bz + (long)ct * 256 * K;

  f32x4 acc[8][4];
#pragma unroll
  for (int m = 0; m < 8; ++m)
#pragma unroll
    for (int n = 0; n < 4; ++n) acc[m][n] = {0.f, 0.f, 0.f, 0.f};

  // stage one K-tile (A: 256x64, B: 256x64) into buf; 8 x gl_lds16 per thread
  auto stage = [&](int buf, int t) {
    const unsigned short* a = Ag + t * 64;
    const unsigned short* b = Bg + t * 64;
#pragma unroll
    for (int r = 0; r < 4; ++r) {
      int c = r * 512 + tid;
      int row = c >> 3, cc = (c & 7) * 8;
      gl_lds16(a + (long)row * K + cc, &sA[buf][c * 8]);
    }
#pragma unroll
    for (int r = 0; r < 4; ++r) {
      int c = r * 512 + tid;
      int row = c >> 3, cc = (c & 7) * 8;
      gl_lds16(b + (long)row * K + cc, &sB[buf][c * 8]);
    }
  };

  const int NT = K >> 6;
  stage(0, 0);
  __syncthreads();  // drains vmcnt -> tile 0 resident
  for (int t = 0; t < NT; ++t) {
    const int cur = t & 1;
    if (t + 1 < NT) stage(cur ^ 1, t + 1);  // issue async loads early
#pragma unroll
    for (int ks = 0; ks < 2; ++ks) {
      bf16x8 bF[4];
#pragma unroll
      for (int n = 0; n < 4; ++n)
        bF[n] = *(const bf16x8*)&sB[cur][(wn * 64 + n * 16 + r16) * 64 + ks * 32 + kgrp * 8];
#pragma unroll
      for (int m = 0; m < 8; ++m) {
        bf16x8 aF = *(const bf16x8*)&sA[cur][(wm * 128 + m * 16 + r16) * 64 + ks * 32 + kgrp * 8];
#pragma unroll
        for (int n = 0; n < 4; ++n)
          acc[m][n] = __builtin_amdgcn_mfma_f32_16x16x32_bf16(aF, bF[n], acc[m][n], 0, 0, 0);
      }
    }
    __syncthreads();  // per-wave vmcnt(0)+lgkmcnt(0) drain: next tile landed, reads done
  }

  const int row0 = rt * 256 + wm * 128;
  const int col0 = ct * 256 + wn * 64;
#pragma unroll
  for (int m = 0; m < 8; ++m) {
#pragma unroll
    for (int n = 0; n < 4; ++n) {
#pragma unroll
      for (int r = 0; r < 4; ++r) {
        float v = acc[m][n][r];
        int row = row0 + m * 16 + kgrp * 4 + r;  // C/D: col=lane&15, row=(lane>>4)*4+r
        int col = col0 + n * 16 + r16;
        if (MODE == 0) {
          float p = __shfl_xor(v, 1);  // RoPE pair partner (col^1, same row/reg)
          int sel = col >> 10;         // 0=Q 1=K 2=V (uniform per 64-col wave slice)
          int lcol = col & 1023;
          if (sel < 2) {
            int pos = row & (C_LEN - 1);
            int i2 = lcol >> 1;
            float c = cosT[pos * (E_DIM / 2) + i2];
            float sn = sinT[pos * (E_DIM / 2) + i2];
            float rv = v * c + ((lcol & 1) ? p * sn : -p * sn);
            unsigned short* o = sel ? oK : oQ;
            o[(long)row * E_DIM + lcol] = f2bf(rv);
          } else {
            int b = row >> 12;
            int cc = row & (C_LEN - 1);
            oVt[(long)b * E_DIM * C_LEN + (long)lcol * C_LEN + cc] = f2bf(v);
          }
        } else if (MODE == 2) {
          float sc = v * 0.03125f + mask[(long)row * C_LEN + col];
          oF[sOb * bz + (long)row * C_LEN + col] = sc;
        } else {
          oF[sOb * bz + (long)row * N + col] = v;
        }
      }
    }
  }
}

// -------- row softmax: normalize f32 weights in place + emit bf16 copy --------
__global__ __launch_bounds__(256) void softmax_rows(float* __restrict__ w,
                                                    unsigned short* __restrict__ pb) {
  long row = blockIdx.x;
  float* p = w + row * C_LEN;
  unsigned short* pbp = pb + row * C_LEN;
  int t = threadIdx.x;
  int wid = t >> 6;
  f32x4 v[4];
  float mx = -3.4e38f;
#pragma unroll
  for (int j = 0; j < 4; ++j) {
    v[j] = *(const f32x4*)(p + j * 1024 + t * 4);
    mx = fmaxf(mx, fmaxf(fmaxf(v[j].x, v[j].y), fmaxf(v[j].z, v[j].w)));
  }
#pragma unroll
  for (int o = 1; o < 64; o <<= 1) mx = fmaxf(mx, __shfl_xor(mx, o));
  __shared__ float redm[4];
  if ((t & 63) == 0) redm[wid] = mx;
  __syncthreads();
  mx = fmaxf(fmaxf(redm[0], redm[1]), fmaxf(redm[2], redm[3]));
  float sum = 0.f;
#pragma unroll
  for (int j = 0; j < 4; ++j) {
    v[j].x = __expf(v[j].x - mx);
    v[j].y = __expf(v[j].y - mx);
    v[j].z = __expf(v[j].z - mx);
    v[j].w = __expf(v[j].w - mx);
    sum += v[j].x + v[j].y + v[j].z + v[j].w;
  }
#pragma unroll
  for (int o = 1; o < 64; o <<= 1) sum += __shfl_xor(sum, o);
  __shared__ float reds[4];
  if ((t & 63) == 0) reds[wid] = sum;
  __syncthreads();
  sum = reds[0] + reds[1] + reds[2] + reds[3];
  float inv = 1.0f / sum;
#pragma unroll
  for (int j = 0; j < 4; ++j) {
    v[j].x *= inv;
    v[j].y *= inv;
    v[j].z *= inv;
    v[j].w *= inv;
    *(f32x4*)(p + j * 1024 + t * 4) = v[j];
    u16x4 o16 = {f2bf(v[j].x), f2bf(v[j].y), f2bf(v[j].z), f2bf(v[j].w)};
    *(u16x4*)(pbp + j * 1024 + t * 4) = o16;
  }
}

extern "C" void kernel_launch(void* const* d_in, const int* in_sizes, int n_in,
                              void* d_out, int out_size, void* d_ws, size_t ws_size,
                              hipStream_t stream) {
  const float* x = (const float*)d_in[0];
  const float* mask = (const float*)d_in[1];
  const float* Wq = (const float*)d_in[2];
  const float* Wk = (const float*)d_in[3];
  const float* Wv = (const float*)d_in[4];
  float* out = (float*)d_out;                           // [B][C][E]
  float* weights = out + (long)NBATCH * C_LEN * E_DIM;  // [B][C][C]

  // ws layout:
  //   cosT 0..8M, sinT 8..16M, x_bf 16..48M, W_bf 48..54M, Q_bf 54..86M, K_bf 86..118M
  //   big ws (>=160MB): Vt at 128..160M; P_bf (4 batches, 128MB) reuses 0..128M after scores
  //   small ws (>=150MB): Vt at 118..150M; P_bf (2 batches, 64MB) at 0; PV in 2 halves
  char* ws = (char*)d_ws;
  const bool big = ws_size >= (160ull << 20);
  float* cosT = (float*)(ws);
  float* sinT = (float*)(ws + (8l << 20));
  unsigned short* x_bf = (unsigned short*)(ws + (16l << 20));
  unsigned short* W_bf = (unsigned short*)(ws + (48l << 20));  // [3072][1024] = Q|K|V
  unsigned short* Q_bf = (unsigned short*)(ws + (54l << 20));
  unsigned short* K_bf = (unsigned short*)(ws + (86l << 20));
  unsigned short* Vt = (unsigned short*)(ws + (big ? (128l << 20) : (118l << 20)));
  unsigned short* P_bf = (unsigned short*)(ws);

  dim3 blk(256);
  dim3 blk512(512);

  rope_table<<<dim3((C_LEN * (E_DIM / 2)) / 256), blk, 0, stream>>>(cosT, sinT);
  cvt_bf16_k<<<dim3(16384), blk, 0, stream>>>(x, x_bf, 4194304);
  cvt_bf16_k<<<dim3(1024), blk, 0, stream>>>(Wq, W_bf, 262144);
  cvt_bf16_k<<<dim3(1024), blk, 0, stream>>>(Wk, W_bf + (1l << 20), 262144);
  cvt_bf16_k<<<dim3(1024), blk, 0, stream>>>(Wv, W_bf + (2l << 20), 262144);

  // fused QKV projection: x[16384][1024] @ W^T -> 64x12 tiles = 768 blocks
  gemm256<0><<<dim3(768), blk512, 0, stream>>>(
      x_bf, W_bf, 0, 0, 0, 64, 12, E_DIM, 3 * E_DIM,
      Q_bf, K_bf, Vt, nullptr, cosT, sinT, nullptr);

  // scores = QK^T/32 + mask -> 16x16 tiles x 4 batches = 1024 blocks
  gemm256<2><<<dim3(1024), blk512, 0, stream>>>(
      Q_bf, K_bf, (long)C_LEN * E_DIM, (long)C_LEN * E_DIM, (long)C_LEN * C_LEN,
      16, 16, E_DIM, C_LEN, nullptr, nullptr, nullptr, weights, nullptr, nullptr, mask);

  if (big) {
    softmax_rows<<<dim3(NBATCH * C_LEN), blk, 0, stream>>>(weights, P_bf);
    // out = P @ V: 16x4 tiles x 4 batches = 256 blocks (1/CU)
    gemm256<3><<<dim3(256), blk512, 0, stream>>>(
        P_bf, Vt, (long)C_LEN * C_LEN, (long)E_DIM * C_LEN, (long)C_LEN * E_DIM,
        16, 4, C_LEN, E_DIM, nullptr, nullptr, nullptr, out, nullptr, nullptr, nullptr);
  } else {
    for (int h = 0; h < 2; ++h) {
      float* wgt = weights + (long)h * 2 * C_LEN * C_LEN;
      softmax_rows<<<dim3(2 * C_LEN), blk, 0, stream>>>(wgt, P_bf);
      gemm256<3><<<dim3(128), blk512, 0, stream>>>(
          P_bf, Vt + (long)h * 2 * E_DIM * C_LEN, (long)C_LEN * C_LEN, (long)E_DIM * C_LEN,
          (long)C_LEN * E_DIM, 16, 4, C_LEN, E_DIM,
          nullptr, nullptr, nullptr, out + (long)h * 2 * C_LEN * E_DIM,
          nullptr, nullptr, nullptr);
    }
  }
}

// Round 4
// 659.051 us; speedup vs baseline: 1.4516x; 1.1984x over previous
//
#include <hip/hip_runtime.h>
#include <cstdint>

#define C_LEN 4096
#define E_DIM 1024
#define NBATCH 4

typedef __attribute__((ext_vector_type(4))) float f32x4;
typedef __attribute__((ext_vector_type(8))) short bf16x8;
typedef __attribute__((ext_vector_type(4))) unsigned short u16x4;

__device__ __forceinline__ unsigned short f2bf(float f) {
  uint32_t u = __builtin_bit_cast(uint32_t, f);
  return (unsigned short)((u + 0x7fffu + ((u >> 16) & 1u)) >> 16);
}

__device__ __forceinline__ void gl_lds16(const void* g, void* l) {
  __builtin_amdgcn_global_load_lds(
      (const __attribute__((address_space(1))) void*)g,
      (__attribute__((address_space(3))) void*)l, 16, 0, 0);
}

// -------- RoPE cos/sin table: [C][E/2] f32 each, computed in double --------
__global__ __launch_bounds__(256) void rope_table(float* __restrict__ cosT,
                                                  float* __restrict__ sinT) {
  int idx = blockIdx.x * 256 + threadIdx.x;  // over C*E/2 = 2,097,152
  int pos = idx >> 9;
  int i = idx & 511;
  double inv = exp(((double)(-2 * i) / 1024.0) * 9.210340371976184);
  double a = (double)pos * inv;
  cosT[idx] = (float)cos(a);
  sinT[idx] = (float)sin(a);
}

// -------- f32 -> bf16 convert (4 elems/thread) --------
__global__ __launch_bounds__(256) void cvt_bf16_k(const float* __restrict__ in,
                                                  unsigned short* __restrict__ out,
                                                  int n4) {
  int i = blockIdx.x * 256 + threadIdx.x;
  if (i < n4) {
    f32x4 v = *(const f32x4*)(in + (long)i * 4);
    u16x4 o = {f2bf(v.x), f2bf(v.y), f2bf(v.z), f2bf(v.w)};
    *(u16x4*)(out + (long)i * 4) = o;
  }
}

// ======== 256x256 8-phase BT GEMM, BK=64, 512 threads = 8 waves (2M x 4N) ========
// T3+T4: 4 phases/K-tile, 1 half-tile staged per phase, vmcnt(6) only at tile end
// (3 half-tiles perpetually in flight). T2: XOR-swizzled LDS (inverse-swizzled
// global source + linear gl_lds dest). T5: setprio around MFMA clusters.
// A[M][K] bf16 row-major, B[N][K] bf16 row-major (B^T form).
// MODE 0: fused QKV projection (N=3072=[Q|K|V]); RoPE on Q/K, transpose-store V.
// MODE 2: epilogue *1/32 + mask, write f32 scores. MODE 3: plain f32 out (PV).
template <int MODE>
__global__ __launch_bounds__(512, 2) void gemm8p(
    const unsigned short* __restrict__ A, const unsigned short* __restrict__ Bm,
    long sAb, long sBb, long sOb, int nr, int nc, int K, int N,
    unsigned short* __restrict__ oQ, unsigned short* __restrict__ oK,
    unsigned short* __restrict__ oVt, float* __restrict__ oF,
    const float* __restrict__ cosT, const float* __restrict__ sinT,
    const float* __restrict__ mask) {
  // [parity][A=0/B=1][half][128 rows x 64 cols], 128 KiB total
  __shared__ unsigned short lds[2][2][2][128 * 64];
  const int tid = threadIdx.x;
  const int lane = tid & 63;
  const int wid = tid >> 6;
  const int wm = wid >> 2, wn = wid & 3;
  const int kgrp = lane >> 4, r16 = lane & 15;
  const int swz = (r16 & 7) << 3;  // element-granular read swizzle

  // bijective XCD swizzle (all grids are multiples of 8)
  const int nwg = gridDim.x;
  const int lid = blockIdx.x;
  const int s = (lid & 7) * (nwg >> 3) + (lid >> 3);
  const int per_b = nr * nc;
  const int bz = s / per_b;
  const int t2 = s - bz * per_b;
  const int rt = t2 / nc, ct = t2 - rt * nc;

  const unsigned short* Ag = A + sAb * bz + (long)rt * 256 * K;
  const unsigned short* Bg = Bm + sBb * bz + (long)ct * 256 * K;

  // Staging: 2 gl_lds per thread per half-tile; LDS dest linear, global src
  // column pre-swizzled by the same involution the reads apply (rule #21).
  const int i0 = tid, i1 = 512 + tid;
  const int sr0 = i0 >> 3, sc0 = ((i0 & 7) ^ (sr0 & 7)) * 8;
  const int sr1 = i1 >> 3, sc1 = ((i1 & 7) ^ (sr1 & 7)) * 8;

  auto stageA = [&](int p, int h, int j) {
    const unsigned short* g = Ag + (long)(h * 128) * K + j * 64;
    gl_lds16(g + (long)sr0 * K + sc0, &lds[p][0][h][i0 * 8]);
    gl_lds16(g + (long)sr1 * K + sc1, &lds[p][0][h][i1 * 8]);
  };
  auto stageB = [&](int p, int h, int j) {
    const unsigned short* g = Bg + (long)(h * 128) * K + j * 64;
    gl_lds16(g + (long)sr0 * K + sc0, &lds[p][1][h][i0 * 8]);
    gl_lds16(g + (long)sr1 * K + sc1, &lds[p][1][h][i1 * 8]);
  };

  f32x4 acc[8][4];
#pragma unroll
  for (int m = 0; m < 8; ++m)
#pragma unroll
    for (int n = 0; n < 4; ++n) acc[m][n] = {0.f, 0.f, 0.f, 0.f};

  const int NT = K >> 6;
  // Prologue: H[0] fully, then H[1] {B0,B1,A0}; retire H[0] (oldest 8), keep 6 in flight.
  stageA(0, 0, 0); stageA(0, 1, 0); stageB(0, 0, 0); stageB(0, 1, 0);
  stageB(1, 0, 1); stageB(1, 1, 1); stageA(1, 0, 1);
  asm volatile("s_waitcnt vmcnt(6)" ::: "memory");
  __builtin_amdgcn_s_barrier();

  for (int j = 0; j < NT; ++j) {
    const int p = j & 1;
    const unsigned short* lA = lds[p][0][wm];        // this wave's A half
    const unsigned short* lB = lds[p][1][wn >> 1];   // this wave's B half
    const int bbase = (wn & 1) * 64;

    bf16x8 aF[8], bF0[4], bF1[4];
    auto rdA = [&](bf16x8* d, int mh) {
#pragma unroll
      for (int m = 0; m < 4; ++m) {
        int lr = mh * 64 + m * 16 + r16;
#pragma unroll
        for (int ks = 0; ks < 2; ++ks)
          d[m * 2 + ks] = *(const bf16x8*)&lA[lr * 64 + ((ks * 32 + kgrp * 8) ^ swz)];
      }
    };
    auto rdB = [&](bf16x8* d, int nh) {
#pragma unroll
      for (int n = 0; n < 2; ++n) {
        int lr = bbase + nh * 32 + n * 16 + r16;
#pragma unroll
        for (int ks = 0; ks < 2; ++ks)
          d[n * 2 + ks] = *(const bf16x8*)&lB[lr * 64 + ((ks * 32 + kgrp * 8) ^ swz)];
      }
    };
    auto mm = [&](bf16x8* af, bf16x8* bf, int mh, int nh) {
      __builtin_amdgcn_s_setprio(1);
#pragma unroll
      for (int ks = 0; ks < 2; ++ks)
#pragma unroll
        for (int m = 0; m < 4; ++m)
#pragma unroll
          for (int n = 0; n < 2; ++n)
            acc[mh * 4 + m][nh * 2 + n] = __builtin_amdgcn_mfma_f32_16x16x32_bf16(
                af[m * 2 + ks], bf[n * 2 + ks], acc[mh * 4 + m][nh * 2 + n], 0, 0, 0);
      __builtin_amdgcn_s_setprio(0);
    };

    // ---- phase 0: read A[mh0]+B[nh0]; stage H[j+1].A-h1 (buffer p^1, idle) ----
    rdA(aF, 0); rdB(bF0, 0);
    if (j + 1 < NT) stageA(p ^ 1, 1, j + 1);
    __builtin_amdgcn_s_barrier();
    asm volatile("s_waitcnt lgkmcnt(0)" ::: "memory");
    __builtin_amdgcn_sched_barrier(0);
    mm(aF, bF0, 0, 0);
    __builtin_amdgcn_s_barrier();
    // ---- phase 1: read B[nh1]; (last B reads of this buffer) ----
    rdB(bF1, 1);
    __builtin_amdgcn_s_barrier();
    asm volatile("s_waitcnt lgkmcnt(0)" ::: "memory");
    __builtin_amdgcn_sched_barrier(0);
    mm(aF, bF1, 0, 1);
    __builtin_amdgcn_s_barrier();
    // ---- phase 2: read A[mh1] (last A reads); stage H[j+2].B-h0 (B sealed @ph1) ----
    rdA(aF, 1);
    if (j + 2 < NT) stageB(p, 0, j + 2);
    __builtin_amdgcn_s_barrier();
    asm volatile("s_waitcnt lgkmcnt(0)" ::: "memory");
    __builtin_amdgcn_sched_barrier(0);
    mm(aF, bF1, 1, 1);
    __builtin_amdgcn_s_barrier();
    // ---- phase 3: no reads; stage H[j+2].{B-h1, A-h0} (A sealed @ph2) ----
    if (j + 2 < NT) { stageB(p, 1, j + 2); stageA(p, 0, j + 2); }
    __builtin_amdgcn_s_barrier();
    mm(aF, bF0, 1, 0);
    // tile-end counted wait: retire H[j+1] (oldest 8), keep H[j+2] (6) in flight
    if (j + 2 < NT) {
      asm volatile("s_waitcnt vmcnt(6)" ::: "memory");
    } else if (j + 1 < NT) {
      asm volatile("s_waitcnt vmcnt(0)" ::: "memory");
    }
    __builtin_amdgcn_s_barrier();
  }

  const int row0 = rt * 256 + wm * 128;
  const int col0 = ct * 256 + wn * 64;
#pragma unroll
  for (int m = 0; m < 8; ++m) {
#pragma unroll
    for (int n = 0; n < 4; ++n) {
#pragma unroll
      for (int r = 0; r < 4; ++r) {
        float v = acc[m][n][r];
        int row = row0 + m * 16 + kgrp * 4 + r;  // C/D: col=lane&15, row=(lane>>4)*4+r
        int col = col0 + n * 16 + r16;
        if (MODE == 0) {
          float pp = __shfl_xor(v, 1);  // RoPE pair partner (col^1, same row/reg)
          int sel = col >> 10;          // 0=Q 1=K 2=V
          int lcol = col & 1023;
          if (sel < 2) {
            int pos = row & (C_LEN - 1);
            int i2 = lcol >> 1;
            float c = cosT[pos * (E_DIM / 2) + i2];
            float sn = sinT[pos * (E_DIM / 2) + i2];
            float rv = v * c + ((lcol & 1) ? pp * sn : -pp * sn);
            unsigned short* o = sel ? oK : oQ;
            o[(long)row * E_DIM + lcol] = f2bf(rv);
          } else {
            int b = row >> 12;
            int cc = row & (C_LEN - 1);
            oVt[(long)b * E_DIM * C_LEN + (long)lcol * C_LEN + cc] = f2bf(v);
          }
        } else if (MODE == 2) {
          float sc = v * 0.03125f + mask[(long)row * C_LEN + col];
          oF[sOb * bz + (long)row * C_LEN + col] = sc;
        } else {
          oF[sOb * bz + (long)row * N + col] = v;
        }
      }
    }
  }
}

// -------- row softmax: normalize f32 weights in place + emit bf16 copy --------
__global__ __launch_bounds__(256) void softmax_rows(float* __restrict__ w,
                                                    unsigned short* __restrict__ pb) {
  long row = blockIdx.x;
  float* p = w + row * C_LEN;
  unsigned short* pbp = pb + row * C_LEN;
  int t = threadIdx.x;
  int wid = t >> 6;
  f32x4 v[4];
  float mx = -3.4e38f;
#pragma unroll
  for (int j = 0; j < 4; ++j) {
    v[j] = *(const f32x4*)(p + j * 1024 + t * 4);
    mx = fmaxf(mx, fmaxf(fmaxf(v[j].x, v[j].y), fmaxf(v[j].z, v[j].w)));
  }
#pragma unroll
  for (int o = 1; o < 64; o <<= 1) mx = fmaxf(mx, __shfl_xor(mx, o));
  __shared__ float redm[4];
  if ((t & 63) == 0) redm[wid] = mx;
  __syncthreads();
  mx = fmaxf(fmaxf(redm[0], redm[1]), fmaxf(redm[2], redm[3]));
  float sum = 0.f;
#pragma unroll
  for (int j = 0; j < 4; ++j) {
    v[j].x = __expf(v[j].x - mx);
    v[j].y = __expf(v[j].y - mx);
    v[j].z = __expf(v[j].z - mx);
    v[j].w = __expf(v[j].w - mx);
    sum += v[j].x + v[j].y + v[j].z + v[j].w;
  }
#pragma unroll
  for (int o = 1; o < 64; o <<= 1) sum += __shfl_xor(sum, o);
  __shared__ float reds[4];
  if ((t & 63) == 0) reds[wid] = sum;
  __syncthreads();
  sum = reds[0] + reds[1] + reds[2] + reds[3];
  float inv = 1.0f / sum;
#pragma unroll
  for (int j = 0; j < 4; ++j) {
    v[j].x *= inv;
    v[j].y *= inv;
    v[j].z *= inv;
    v[j].w *= inv;
    *(f32x4*)(p + j * 1024 + t * 4) = v[j];
    u16x4 o16 = {f2bf(v[j].x), f2bf(v[j].y), f2bf(v[j].z), f2bf(v[j].w)};
    *(u16x4*)(pbp + j * 1024 + t * 4) = o16;
  }
}

extern "C" void kernel_launch(void* const* d_in, const int* in_sizes, int n_in,
                              void* d_out, int out_size, void* d_ws, size_t ws_size,
                              hipStream_t stream) {
  const float* x = (const float*)d_in[0];
  const float* mask = (const float*)d_in[1];
  const float* Wq = (const float*)d_in[2];
  const float* Wk = (const float*)d_in[3];
  const float* Wv = (const float*)d_in[4];
  float* out = (float*)d_out;                           // [B][C][E]
  float* weights = out + (long)NBATCH * C_LEN * E_DIM;  // [B][C][C]

  char* ws = (char*)d_ws;
  const bool big = ws_size >= (160ull << 20);
  float* cosT = (float*)(ws);
  float* sinT = (float*)(ws + (8l << 20));
  unsigned short* x_bf = (unsigned short*)(ws + (16l << 20));
  unsigned short* W_bf = (unsigned short*)(ws + (48l << 20));  // [3072][1024] = Q|K|V
  unsigned short* Q_bf = (unsigned short*)(ws + (54l << 20));
  unsigned short* K_bf = (unsigned short*)(ws + (86l << 20));
  unsigned short* Vt = (unsigned short*)(ws + (big ? (128l << 20) : (118l << 20)));
  unsigned short* P_bf = (unsigned short*)(ws);

  dim3 blk(256);
  dim3 blk512(512);

  rope_table<<<dim3((C_LEN * (E_DIM / 2)) / 256), blk, 0, stream>>>(cosT, sinT);
  cvt_bf16_k<<<dim3(16384), blk, 0, stream>>>(x, x_bf, 4194304);
  cvt_bf16_k<<<dim3(1024), blk, 0, stream>>>(Wq, W_bf, 262144);
  cvt_bf16_k<<<dim3(1024), blk, 0, stream>>>(Wk, W_bf + (1l << 20), 262144);
  cvt_bf16_k<<<dim3(1024), blk, 0, stream>>>(Wv, W_bf + (2l << 20), 262144);

  // fused QKV projection: x[16384][1024] @ W^T -> 64x12 tiles = 768 blocks
  gemm8p<0><<<dim3(768), blk512, 0, stream>>>(
      x_bf, W_bf, 0, 0, 0, 64, 12, E_DIM, 3 * E_DIM,
      Q_bf, K_bf, Vt, nullptr, cosT, sinT, nullptr);

  // scores = QK^T/32 + mask -> 16x16 tiles x 4 batches = 1024 blocks
  gemm8p<2><<<dim3(1024), blk512, 0, stream>>>(
      Q_bf, K_bf, (long)C_LEN * E_DIM, (long)C_LEN * E_DIM, (long)C_LEN * C_LEN,
      16, 16, E_DIM, C_LEN, nullptr, nullptr, nullptr, weights, nullptr, nullptr, mask);

  if (big) {
    softmax_rows<<<dim3(NBATCH * C_LEN), blk, 0, stream>>>(weights, P_bf);
    gemm8p<3><<<dim3(256), blk512, 0, stream>>>(
        P_bf, Vt, (long)C_LEN * C_LEN, (long)E_DIM * C_LEN, (long)C_LEN * E_DIM,
        16, 4, C_LEN, E_DIM, nullptr, nullptr, nullptr, out, nullptr, nullptr, nullptr);
  } else {
    for (int h = 0; h < 2; ++h) {
      float* wgt = weights + (long)h * 2 * C_LEN * C_LEN;
      softmax_rows<<<dim3(2 * C_LEN), blk, 0, stream>>>(wgt, P_bf);
      gemm8p<3><<<dim3(128), blk512, 0, stream>>>(
          P_bf, Vt + (long)h * 2 * E_DIM * C_LEN, (long)C_LEN * C_LEN, (long)E_DIM * C_LEN,
          (long)C_LEN * E_DIM, 16, 4, C_LEN, E_DIM,
          nullptr, nullptr, nullptr, out + (long)h * 2 * C_LEN * E_DIM,
          nullptr, nullptr, nullptr);
    }
  }
}

// Round 5
// 642.005 us; speedup vs baseline: 1.4902x; 1.0266x over previous
//
#include <hip/hip_runtime.h>
#include <cstdint>

#define C_LEN 4096
#define E_DIM 1024
#define NBATCH 4

typedef __attribute__((ext_vector_type(4))) float f32x4;
typedef __attribute__((ext_vector_type(8))) short bf16x8;
typedef __attribute__((ext_vector_type(4))) unsigned short u16x4;

__device__ __forceinline__ unsigned short f2bf(float f) {
  uint32_t u = __builtin_bit_cast(uint32_t, f);
  return (unsigned short)((u + 0x7fffu + ((u >> 16) & 1u)) >> 16);
}

__device__ __forceinline__ void gl_lds16(const void* g, void* l) {
  __builtin_amdgcn_global_load_lds(
      (const __attribute__((address_space(1))) void*)g,
      (__attribute__((address_space(3))) void*)l, 16, 0, 0);
}

// -------- RoPE cos/sin table: [C][E/2] f32 each --------
// inv_freq + angle in double (matches round-1..4 absmax 1.46e-3), then
// double range-reduction + fast f32 sincos (err ~1e-6, negligible).
__global__ __launch_bounds__(256) void rope_table(float* __restrict__ cosT,
                                                  float* __restrict__ sinT) {
  int idx = blockIdx.x * 256 + threadIdx.x;  // over C*E/2
  int pos = idx >> 9;
  int i = idx & 511;
  double inv = exp(((double)(-2 * i) / 1024.0) * 9.210340371976184);
  double a = (double)pos * inv;
  double r = a - 6.283185307179586 * rint(a * 0.15915494309189535);
  float rf = (float)r;
  float s, c;
  __sincosf(rf, &s, &c);
  cosT[idx] = c;
  sinT[idx] = s;
}

// -------- fused f32 -> bf16 convert for x, Wq, Wk, Wv --------
__global__ __launch_bounds__(256) void cvt_all(const float* __restrict__ x,
                                               const float* __restrict__ wq,
                                               const float* __restrict__ wk,
                                               const float* __restrict__ wv,
                                               unsigned short* __restrict__ x_bf,
                                               unsigned short* __restrict__ w_bf) {
  int b = blockIdx.x;
  const float* in;
  unsigned short* out;
  long off;
  if (b < 16384) { in = x; out = x_bf; off = (long)b * 1024; }
  else if (b < 17408) { in = wq; out = w_bf; off = (long)(b - 16384) * 1024; }
  else if (b < 18432) { in = wk; out = w_bf + (1l << 20); off = (long)(b - 17408) * 1024; }
  else { in = wv; out = w_bf + (2l << 20); off = (long)(b - 18432) * 1024; }
  long i = off + threadIdx.x * 4;
  f32x4 v = *(const f32x4*)(in + i);
  u16x4 o = {f2bf(v.x), f2bf(v.y), f2bf(v.z), f2bf(v.w)};
  *(u16x4*)(out + i) = o;
}

// ======== 256x256 8-phase BT GEMM, BK=64, 512 threads = 8 waves (2M x 4N) ========
// T3+T4 counted vmcnt, T2 swizzle (0 bank conflicts measured), T5 setprio,
// T1 XCD chunk + 4x4 supertile decode (2MB A + 2MB B per supertile -> fits 4MB L2),
// nontemporal stores on streamed f32 outputs (keep operand panels in L2/LLC).
// MODE 0: fused QKV projection (N=3072=[Q|K|V]); RoPE on Q/K, transpose-store V.
// MODE 2: epilogue *1/32 + mask, NT-write f32 scores. MODE 3: NT f32 out (PV).
template <int MODE>
__global__ __launch_bounds__(512, 1) void gemm8p(
    const unsigned short* __restrict__ A, const unsigned short* __restrict__ Bm,
    long sAb, long sBb, long sOb, int nr, int nc, int K, int N,
    unsigned short* __restrict__ oQ, unsigned short* __restrict__ oK,
    unsigned short* __restrict__ oVt, float* __restrict__ oF,
    const float* __restrict__ cosT, const float* __restrict__ sinT,
    const float* __restrict__ mask) {
  // [parity][A=0/B=1][half][128 rows x 64 cols], 128 KiB total
  __shared__ unsigned short lds[2][2][2][128 * 64];
  const int tid = threadIdx.x;
  const int lane = tid & 63;
  const int wid = tid >> 6;
  const int wm = wid >> 2, wn = wid & 3;
  const int kgrp = lane >> 4, r16 = lane & 15;
  const int swz = (r16 & 7) << 3;  // element-granular read swizzle

  // XCD chunk (grids are multiples of 8) + 4x4 supertile decode (nr%4==nc%4==0)
  const int nwg = gridDim.x;
  const int lid = blockIdx.x;
  const int s = (lid & 7) * (nwg >> 3) + (lid >> 3);
  const int scc = nc >> 2;
  const int per_b_st = (nr >> 2) * scc;
  const int sid = s >> 4, inner = s & 15;
  const int bz = sid / per_b_st;
  const int r2 = sid - bz * per_b_st;
  const int srt = r2 / scc, sct = r2 - srt * scc;
  const int rt = srt * 4 + (inner >> 2), ct = sct * 4 + (inner & 3);

  const unsigned short* Ag = A + sAb * bz + (long)rt * 256 * K;
  const unsigned short* Bg = Bm + sBb * bz + (long)ct * 256 * K;

  // Staging: LDS dest linear, global src column pre-swizzled by the read involution.
  const int i0 = tid, i1 = 512 + tid;
  const int sr0 = i0 >> 3, sc0 = ((i0 & 7) ^ (sr0 & 7)) * 8;
  const int sr1 = i1 >> 3, sc1 = ((i1 & 7) ^ (sr1 & 7)) * 8;

  auto stageA = [&](int p, int h, int j) {
    const unsigned short* g = Ag + (long)(h * 128) * K + j * 64;
    gl_lds16(g + (long)sr0 * K + sc0, &lds[p][0][h][i0 * 8]);
    gl_lds16(g + (long)sr1 * K + sc1, &lds[p][0][h][i1 * 8]);
  };
  auto stageB = [&](int p, int h, int j) {
    const unsigned short* g = Bg + (long)(h * 128) * K + j * 64;
    gl_lds16(g + (long)sr0 * K + sc0, &lds[p][1][h][i0 * 8]);
    gl_lds16(g + (long)sr1 * K + sc1, &lds[p][1][h][i1 * 8]);
  };

  f32x4 acc[8][4];
#pragma unroll
  for (int m = 0; m < 8; ++m)
#pragma unroll
    for (int n = 0; n < 4; ++n) acc[m][n] = {0.f, 0.f, 0.f, 0.f};

  const int NT = K >> 6;
  // Prologue: H[0] fully, then H[1] {B0,B1,A0}; retire H[0] (oldest 8), keep 6 in flight.
  stageA(0, 0, 0); stageA(0, 1, 0); stageB(0, 0, 0); stageB(0, 1, 0);
  stageB(1, 0, 1); stageB(1, 1, 1); stageA(1, 0, 1);
  asm volatile("s_waitcnt vmcnt(6)" ::: "memory");
  __builtin_amdgcn_s_barrier();

  for (int j = 0; j < NT; ++j) {
    const int p = j & 1;
    const unsigned short* lA = lds[p][0][wm];        // this wave's A half
    const unsigned short* lB = lds[p][1][wn >> 1];   // this wave's B half
    const int bbase = (wn & 1) * 64;

    bf16x8 aF[8], bF0[4], bF1[4];
    auto rdA = [&](bf16x8* d, int mh) {
#pragma unroll
      for (int m = 0; m < 4; ++m) {
        int lr = mh * 64 + m * 16 + r16;
#pragma unroll
        for (int ks = 0; ks < 2; ++ks)
          d[m * 2 + ks] = *(const bf16x8*)&lA[lr * 64 + ((ks * 32 + kgrp * 8) ^ swz)];
      }
    };
    auto rdB = [&](bf16x8* d, int nh) {
#pragma unroll
      for (int n = 0; n < 2; ++n) {
        int lr = bbase + nh * 32 + n * 16 + r16;
#pragma unroll
        for (int ks = 0; ks < 2; ++ks)
          d[n * 2 + ks] = *(const bf16x8*)&lB[lr * 64 + ((ks * 32 + kgrp * 8) ^ swz)];
      }
    };
    auto mm = [&](bf16x8* af, bf16x8* bf, int mh, int nh) {
      __builtin_amdgcn_s_setprio(1);
#pragma unroll
      for (int ks = 0; ks < 2; ++ks)
#pragma unroll
        for (int m = 0; m < 4; ++m)
#pragma unroll
          for (int n = 0; n < 2; ++n)
            acc[mh * 4 + m][nh * 2 + n] = __builtin_amdgcn_mfma_f32_16x16x32_bf16(
                af[m * 2 + ks], bf[n * 2 + ks], acc[mh * 4 + m][nh * 2 + n], 0, 0, 0);
      __builtin_amdgcn_s_setprio(0);
    };

    // ---- phase 0: read A[mh0]+B[nh0]; stage H[j+1].A-h1 (buffer p^1, idle) ----
    rdA(aF, 0); rdB(bF0, 0);
    if (j + 1 < NT) stageA(p ^ 1, 1, j + 1);
    __builtin_amdgcn_s_barrier();
    asm volatile("s_waitcnt lgkmcnt(0)" ::: "memory");
    __builtin_amdgcn_sched_barrier(0);
    mm(aF, bF0, 0, 0);
    __builtin_amdgcn_s_barrier();
    // ---- phase 1: read B[nh1]; (last B reads of this buffer) ----
    rdB(bF1, 1);
    __builtin_amdgcn_s_barrier();
    asm volatile("s_waitcnt lgkmcnt(0)" ::: "memory");
    __builtin_amdgcn_sched_barrier(0);
    mm(aF, bF1, 0, 1);
    __builtin_amdgcn_s_barrier();
    // ---- phase 2: read A[mh1] (last A reads); stage H[j+2].B-h0 (B sealed @ph1) ----
    rdA(aF, 1);
    if (j + 2 < NT) stageB(p, 0, j + 2);
    __builtin_amdgcn_s_barrier();
    asm volatile("s_waitcnt lgkmcnt(0)" ::: "memory");
    __builtin_amdgcn_sched_barrier(0);
    mm(aF, bF1, 1, 1);
    __builtin_amdgcn_s_barrier();
    // ---- phase 3: no reads; stage H[j+2].{B-h1, A-h0} (A sealed @ph2) ----
    if (j + 2 < NT) { stageB(p, 1, j + 2); stageA(p, 0, j + 2); }
    __builtin_amdgcn_s_barrier();
    mm(aF, bF0, 1, 0);
    // tile-end counted wait: retire oldest, keep 6 (3 half-tiles) in flight
    if (j + 2 < NT) {
      asm volatile("s_waitcnt vmcnt(6)" ::: "memory");
    } else if (j + 1 < NT) {
      asm volatile("s_waitcnt vmcnt(0)" ::: "memory");
    }
    __builtin_amdgcn_s_barrier();
  }

  const int row0 = rt * 256 + wm * 128;
  const int col0 = ct * 256 + wn * 64;
#pragma unroll
  for (int m = 0; m < 8; ++m) {
#pragma unroll
    for (int n = 0; n < 4; ++n) {
#pragma unroll
      for (int r = 0; r < 4; ++r) {
        float v = acc[m][n][r];
        int row = row0 + m * 16 + kgrp * 4 + r;  // C/D: col=lane&15, row=(lane>>4)*4+r
        int col = col0 + n * 16 + r16;
        if (MODE == 0) {
          float pp = __shfl_xor(v, 1);  // RoPE pair partner (col^1, same row/reg)
          int sel = col >> 10;          // 0=Q 1=K 2=V
          int lcol = col & 1023;
          if (sel < 2) {
            int pos = row & (C_LEN - 1);
            int i2 = lcol >> 1;
            float c = cosT[pos * (E_DIM / 2) + i2];
            float sn = sinT[pos * (E_DIM / 2) + i2];
            float rv = v * c + ((lcol & 1) ? pp * sn : -pp * sn);
            unsigned short* o = sel ? oK : oQ;
            o[(long)row * E_DIM + lcol] = f2bf(rv);
          } else {
            int b = row >> 12;
            int cc = row & (C_LEN - 1);
            oVt[(long)b * E_DIM * C_LEN + (long)lcol * C_LEN + cc] = f2bf(v);
          }
        } else if (MODE == 2) {
          float sc = v * 0.03125f + mask[(long)row * C_LEN + col];
          __builtin_nontemporal_store(sc, &oF[sOb * bz + (long)row * C_LEN + col]);
        } else {
          __builtin_nontemporal_store(v, &oF[sOb * bz + (long)row * N + col]);
        }
      }
    }
  }
}

// -------- row softmax: normalize f32 weights in place + emit bf16 copy --------
// NT-load raw scores (one-shot read), NT-store final f32 weights (never re-read).
__global__ __launch_bounds__(256) void softmax_rows(float* __restrict__ w,
                                                    unsigned short* __restrict__ pb) {
  long row = blockIdx.x;
  float* p = w + row * C_LEN;
  unsigned short* pbp = pb + row * C_LEN;
  int t = threadIdx.x;
  int wid = t >> 6;
  f32x4 v[4];
  float mx = -3.4e38f;
#pragma unroll
  for (int j = 0; j < 4; ++j) {
    v[j] = __builtin_nontemporal_load((const f32x4*)(p + j * 1024 + t * 4));
    mx = fmaxf(mx, fmaxf(fmaxf(v[j].x, v[j].y), fmaxf(v[j].z, v[j].w)));
  }
#pragma unroll
  for (int o = 1; o < 64; o <<= 1) mx = fmaxf(mx, __shfl_xor(mx, o));
  __shared__ float redm[4];
  if ((t & 63) == 0) redm[wid] = mx;
  __syncthreads();
  mx = fmaxf(fmaxf(redm[0], redm[1]), fmaxf(redm[2], redm[3]));
  float sum = 0.f;
#pragma unroll
  for (int j = 0; j < 4; ++j) {
    v[j].x = __expf(v[j].x - mx);
    v[j].y = __expf(v[j].y - mx);
    v[j].z = __expf(v[j].z - mx);
    v[j].w = __expf(v[j].w - mx);
    sum += v[j].x + v[j].y + v[j].z + v[j].w;
  }
#pragma unroll
  for (int o = 1; o < 64; o <<= 1) sum += __shfl_xor(sum, o);
  __shared__ float reds[4];
  if ((t & 63) == 0) reds[wid] = sum;
  __syncthreads();
  sum = reds[0] + reds[1] + reds[2] + reds[3];
  float inv = 1.0f / sum;
#pragma unroll
  for (int j = 0; j < 4; ++j) {
    v[j].x *= inv;
    v[j].y *= inv;
    v[j].z *= inv;
    v[j].w *= inv;
    __builtin_nontemporal_store(v[j], (f32x4*)(p + j * 1024 + t * 4));
    u16x4 o16 = {f2bf(v[j].x), f2bf(v[j].y), f2bf(v[j].z), f2bf(v[j].w)};
    *(u16x4*)(pbp + j * 1024 + t * 4) = o16;
  }
}

extern "C" void kernel_launch(void* const* d_in, const int* in_sizes, int n_in,
                              void* d_out, int out_size, void* d_ws, size_t ws_size,
                              hipStream_t stream) {
  const float* x = (const float*)d_in[0];
  const float* mask = (const float*)d_in[1];
  const float* Wq = (const float*)d_in[2];
  const float* Wk = (const float*)d_in[3];
  const float* Wv = (const float*)d_in[4];
  float* out = (float*)d_out;                           // [B][C][E]
  float* weights = out + (long)NBATCH * C_LEN * E_DIM;  // [B][C][C]

  char* ws = (char*)d_ws;
  const bool big = ws_size >= (160ull << 20);
  float* cosT = (float*)(ws);
  float* sinT = (float*)(ws + (8l << 20));
  unsigned short* x_bf = (unsigned short*)(ws + (16l << 20));
  unsigned short* W_bf = (unsigned short*)(ws + (48l << 20));  // [3072][1024] = Q|K|V
  unsigned short* Q_bf = (unsigned short*)(ws + (54l << 20));
  unsigned short* K_bf = (unsigned short*)(ws + (86l << 20));
  unsigned short* Vt = (unsigned short*)(ws + (big ? (128l << 20) : (118l << 20)));
  unsigned short* P_bf = (unsigned short*)(ws);

  dim3 blk(256);
  dim3 blk512(512);

  rope_table<<<dim3((C_LEN * (E_DIM / 2)) / 256), blk, 0, stream>>>(cosT, sinT);
  cvt_all<<<dim3(19456), blk, 0, stream>>>(x, Wq, Wk, Wv, x_bf, W_bf);

  // fused QKV projection: x[16384][1024] @ W^T -> 64x12 tiles = 768 blocks
  gemm8p<0><<<dim3(768), blk512, 0, stream>>>(
      x_bf, W_bf, 0, 0, 0, 64, 12, E_DIM, 3 * E_DIM,
      Q_bf, K_bf, Vt, nullptr, cosT, sinT, nullptr);

  // scores = QK^T/32 + mask -> 16x16 tiles x 4 batches = 1024 blocks
  gemm8p<2><<<dim3(1024), blk512, 0, stream>>>(
      Q_bf, K_bf, (long)C_LEN * E_DIM, (long)C_LEN * E_DIM, (long)C_LEN * C_LEN,
      16, 16, E_DIM, C_LEN, nullptr, nullptr, nullptr, weights, nullptr, nullptr, mask);

  if (big) {
    softmax_rows<<<dim3(NBATCH * C_LEN), blk, 0, stream>>>(weights, P_bf);
    gemm8p<3><<<dim3(256), blk512, 0, stream>>>(
        P_bf, Vt, (long)C_LEN * C_LEN, (long)E_DIM * C_LEN, (long)C_LEN * E_DIM,
        16, 4, C_LEN, E_DIM, nullptr, nullptr, nullptr, out, nullptr, nullptr, nullptr);
  } else {
    for (int h = 0; h < 2; ++h) {
      float* wgt = weights + (long)h * 2 * C_LEN * C_LEN;
      softmax_rows<<<dim3(2 * C_LEN), blk, 0, stream>>>(wgt, P_bf);
      gemm8p<3><<<dim3(128), blk512, 0, stream>>>(
          P_bf, Vt + (long)h * 2 * E_DIM * C_LEN, (long)C_LEN * C_LEN, (long)E_DIM * C_LEN,
          (long)C_LEN * E_DIM, 16, 4, C_LEN, E_DIM,
          nullptr, nullptr, nullptr, out + (long)h * 2 * C_LEN * E_DIM,
          nullptr, nullptr, nullptr);
    }
  }
}